// Round 4
// baseline (116.907 us; speedup 1.0000x reference)
//
#include <hip/hip_runtime.h>
#include <hip/hip_fp16.h>

typedef _Float16 f16x8 __attribute__((ext_vector_type(8)));
typedef _Float16 f16x4 __attribute__((ext_vector_type(4)));
typedef float f32x4 __attribute__((ext_vector_type(4)));

#define D_MODEL 1024
#define SEQ 1024
#define BATCH 4
#define NH 16
#define DV 64
#define M_TOTAL (BATCH * SEQ)   // 4096
#define QBLK 128

__device__ __forceinline__ void gload16(const _Float16* g, _Float16* lds) {
    __builtin_amdgcn_global_load_lds((const __attribute__((address_space(1))) void*)g,
                                     (__attribute__((address_space(3))) void*)lds,
                                     16, 0, 0);
}

// ---------------- fp32 -> fp16 convert (8 elems/thread) ----------------
__global__ void cvt_f32_f16(const float* __restrict__ s, _Float16* __restrict__ d, int n) {
    int i = (blockIdx.x * blockDim.x + threadIdx.x) * 8;
    if (i >= n) return;
    float4 a = *(const float4*)(s + i);
    float4 b = *(const float4*)(s + i + 4);
    f16x8 h;
    h[0] = (_Float16)a.x; h[1] = (_Float16)a.y; h[2] = (_Float16)a.z; h[3] = (_Float16)a.w;
    h[4] = (_Float16)b.x; h[5] = (_Float16)b.y; h[6] = (_Float16)b.z; h[7] = (_Float16)b.w;
    *(f16x8*)(d + i) = h;
}

__global__ void cvt3_f32_f16(const float* __restrict__ s0, const float* __restrict__ s1,
                             const float* __restrict__ s2, _Float16* __restrict__ d0,
                             _Float16* __restrict__ d1, _Float16* __restrict__ d2, int n) {
    const float* s = (blockIdx.y == 0) ? s0 : (blockIdx.y == 1 ? s1 : s2);
    _Float16*    d = (blockIdx.y == 0) ? d0 : (blockIdx.y == 1 ? d1 : d2);
    int i = (blockIdx.x * blockDim.x + threadIdx.x) * 8;
    if (i >= n) return;
    float4 a = *(const float4*)(s + i);
    float4 b = *(const float4*)(s + i + 4);
    f16x8 h;
    h[0] = (_Float16)a.x; h[1] = (_Float16)a.y; h[2] = (_Float16)a.z; h[3] = (_Float16)a.w;
    h[4] = (_Float16)b.x; h[5] = (_Float16)b.y; h[6] = (_Float16)b.z; h[7] = (_Float16)b.w;
    *(f16x8*)(d + i) = h;
}

// ---------------- fused QKV projection GEMM: 256x256 8-phase (T2+T3+T4+T5) ----------------
// C[m,o] = sum_k X[m,k] * W[o,k] + b[o]  (NT GEMM over concatenated N = 3x1024).
// 512 threads = 8 waves (2M x 4N), per-wave 128x64 output, BK=64, 16 K-tiles.
// LDS 128 KiB: A/B 256x64 fp16, double-buffered, XOR chunk-swizzle via pre-swizzled
// global source (dest linear for global_load_lds). Per 8-phase pair-iteration:
// phases 0-3 compute tile t0 (buf0), 4-7 tile t1 (buf1); each phase stages one
// 128-row half-tile (2 x global_load_lds); s_waitcnt vmcnt(4) ONLY at phases 3/7.
// Stage ledger (steady state, per-wave queue):
//   top of iter: outstanding = B(t1) [4]
//   ph0,1: +A(t1)->buf1.A   [consumed rows were read last iter ph4-7]
//   ph2,3: +B(t0+2)->buf0.B [buf0.B consumed at ph0]
//   ph3 end: vmcnt(4) -> B(t1),A(t1) complete (needed ph4-7)
//   ph4,5: +A(t0+2)->buf0.A [buf0.A consumed by ph3]
//   ph6,7: +B(t1+2)->buf1.B [buf1.B consumed at ph4]
//   ph7 end: vmcnt(4) -> B(t0+2),A(t0+2) complete (needed next ph0-3)
__global__ __launch_bounds__(512, 2) void qkv_gemm(
    const _Float16* __restrict__ X,
    const _Float16* __restrict__ W0, const _Float16* __restrict__ W1, const _Float16* __restrict__ W2,
    const float* __restrict__ b0, const float* __restrict__ b1, const float* __restrict__ b2,
    _Float16* __restrict__ Qo, _Float16* __restrict__ Ko, _Float16* __restrict__ Vto)
{
    __shared__ _Float16 As[2][256 * 64];
    __shared__ _Float16 Bs[2][256 * 64];

    const int tid = threadIdx.x;
    const int l = tid & 63;
    const int w = tid >> 6;
    const int wr = w >> 2, wc = w & 3;

    // 192 blocks = 8 XCD x 24; ntg-contiguous per XCD (W panel L2-resident)
    const int bid = blockIdx.x;
    const int nid = (bid & 7) * 24 + (bid >> 3);
    const int mt = nid & 15, ntg = nid >> 4;      // ntg 0..11
    const int mat = ntg >> 2, nt = ntg & 3;       // mat: 0=Q 1=K 2=V
    const _Float16* Wm  = (mat == 0) ? W0 : (mat == 1 ? W1 : W2);
    const float*    bia = (mat == 0) ? b0 : (mat == 1 ? b1 : b2);
    const int m0 = mt * 256, n0 = nt * 256;

    // staging: instr covers 64 rows; thread t -> row (t>>3), dest chunk t&7,
    // source chunk (t&7)^(row&7) (swizzle involution per 8-row stripe)
    const int str = tid >> 3;
    const int sc8 = ((tid & 7) ^ (str & 7)) * 8;
    const _Float16* xsrc = X  + (size_t)(m0 + str) * D_MODEL + sc8;
    const _Float16* wsrc = Wm + (size_t)(n0 + str) * D_MODEL + sc8;
    const int ldst = str * 64 + (tid & 7) * 8;    // = w*512 + l*8 halves (base + lane*16B)

#define SA(buf, kt, h) do { \
    gload16(xsrc + (size_t)((h) * 128) * D_MODEL + (kt) * 64, &As[buf][(h) * 128 * 64] + ldst); \
    gload16(xsrc + (size_t)((h) * 128 + 64) * D_MODEL + (kt) * 64, &As[buf][((h) * 128 + 64) * 64] + ldst); } while (0)
#define SB(buf, kt, h) do { \
    gload16(wsrc + (size_t)((h) * 128) * D_MODEL + (kt) * 64, &Bs[buf][(h) * 128 * 64] + ldst); \
    gload16(wsrc + (size_t)((h) * 128 + 64) * D_MODEL + (kt) * 64, &Bs[buf][((h) * 128 + 64) * 64] + ldst); } while (0)

    const int fr = l & 15, g = l >> 4, fr7 = l & 7;
    const int wrow = wr * 128, bcol = wc * 64;

    f32x4 acc[8][4] = {};
    f16x8 b[4][2];

    // prologue: B(0), A(0), B(1) in exactly this issue order
    SB(0, 0, 0); SB(0, 0, 1);
    SA(0, 0, 0); SA(0, 0, 1);
    SB(1, 1, 0); SB(1, 1, 1);
    asm volatile("s_waitcnt vmcnt(4)" ::: "memory");   // B(0),A(0) done; B(1) in flight
    __builtin_amdgcn_s_barrier();

#define PHASES(BUF, TSA_BUF, TSA, TSB_BUF, TSB)                                              \
    _Pragma("unroll")                                                                        \
    for (int p = 0; p < 4; ++p) {                                                            \
        if (p == 0) {                                                                        \
            _Pragma("unroll")                                                                \
            for (int nj = 0; nj < 4; ++nj) {                                                 \
                const int rb = (bcol + nj * 16 + fr) * 64;                                   \
                b[nj][0] = *(const f16x8*)&Bs[BUF][rb + ((g ^ fr7) << 3)];                   \
                b[nj][1] = *(const f16x8*)&Bs[BUF][rb + (((4 + g) ^ fr7) << 3)];             \
            }                                                                                \
        }                                                                                    \
        f16x8 aq[2][2];                                                                      \
        _Pragma("unroll")                                                                    \
        for (int q = 0; q < 2; ++q) {                                                        \
            const int ra = (wrow + (2 * p + q) * 16 + fr) * 64;                              \
            aq[q][0] = *(const f16x8*)&As[BUF][ra + ((g ^ fr7) << 3)];                       \
            aq[q][1] = *(const f16x8*)&As[BUF][ra + (((4 + g) ^ fr7) << 3)];                 \
        }                                                                                    \
        if (p == 0) SA(TSA_BUF, TSA, 0);                                                     \
        else if (p == 1) SA(TSA_BUF, TSA, 1);                                                \
        else if (p == 2) SB(TSB_BUF, TSB, 0);                                                \
        else SB(TSB_BUF, TSB, 1);                                                            \
        __builtin_amdgcn_s_barrier();                                                        \
        __builtin_amdgcn_s_setprio(1);                                                       \
        _Pragma("unroll")                                                                    \
        for (int ks = 0; ks < 2; ++ks)                                                       \
            _Pragma("unroll")                                                                \
            for (int q = 0; q < 2; ++q)                                                      \
                _Pragma("unroll")                                                            \
                for (int nj = 0; nj < 4; ++nj)                                               \
                    acc[2 * p + q][nj] = __builtin_amdgcn_mfma_f32_16x16x32_f16(             \
                        aq[q][ks], b[nj][ks], acc[2 * p + q][nj], 0, 0, 0);                  \
        __builtin_amdgcn_s_setprio(0);                                                       \
        if (p == 3) asm volatile("s_waitcnt vmcnt(4)" ::: "memory");                         \
        __builtin_amdgcn_s_barrier();                                                        \
    }

    for (int it = 0; it < 8; ++it) {
        const int tA = 2 * it + 1;
        const int tN = (2 * it + 2 < 16) ? 2 * it + 2 : 15;   // clamped: dummy stores land
        const int tM = (2 * it + 3 < 16) ? 2 * it + 3 : 15;   // in already-consumed regions
        PHASES(0, 1, tA, 0, tN)   // tile t0 from buf0; stage A(t1)->buf1, B(t0+2)->buf0
        PHASES(1, 0, tN, 1, tM)   // tile t1 from buf1; stage A(t0+2)->buf0, B(t1+2)->buf1
    }
#undef PHASES
#undef SA
#undef SB

    // epilogue: bias + (Q only) 0.125/ln2 scale, scatter to per-head layouts
    const float scale = (mat == 0) ? 0.125f * 1.44269504088896340736f : 1.0f;
#pragma unroll
    for (int nj = 0; nj < 4; ++nj) {
        const int o = n0 + bcol + nj * 16 + fr;
        const float bb = bia[o];
        const int h = o >> 6, dd = o & 63;
#pragma unroll
        for (int mi = 0; mi < 8; ++mi) {
#pragma unroll
            for (int r = 0; r < 4; ++r) {
                const int m = m0 + wrow + mi * 16 + g * 4 + r;
                const int bi = m >> 10, s = m & 1023;
                const float v = (acc[mi][nj][r] + bb) * scale;
                const _Float16 hv = (_Float16)v;
                const int bh = bi * NH + h;
                if (mat == 0)      Qo[((size_t)bh * SEQ + s) * DV + dd] = hv;
                else if (mat == 1) Ko[((size_t)bh * SEQ + s) * DV + dd] = hv;
                else               Vto[((size_t)bh * DV + dd) * SEQ + s] = hv;
            }
        }
    }
}

// ---------------- flash attention (unchanged, known-good) ----------------
__global__ __launch_bounds__(256) void attn(
    const _Float16* __restrict__ Q, const _Float16* __restrict__ K,
    const _Float16* __restrict__ Vt, float* __restrict__ out)
{
    __shared__ _Float16 Kb[2][64 * 64];
    __shared__ _Float16 Vb[2][64 * 64];
    __shared__ _Float16 P[4][2][16][80];

    const int w = threadIdx.x >> 6, l = threadIdx.x & 63;
    const int qc = l & 15, g = l >> 4;

    const int fid = blockIdx.y * 8 + blockIdx.x;        // grid = (8, 64)
    const int nid = (fid & 7) * 64 + (fid >> 3);
    const int bh = nid >> 3, qt = nid & 7;
    const int b = bh >> 4, h = bh & 15;
    const int q0 = qt * QBLK + w * 32;

    const int r8 = l >> 3;
    const int cs = ((l & 7) ^ r8) * 8;
    const _Float16* Kg = K  + (size_t)bh * SEQ * DV;
    const _Float16* Vg = Vt + (size_t)bh * DV * SEQ;

    f16x8 qf[2][2];
#pragma unroll
    for (int qg = 0; qg < 2; ++qg) {
        const _Float16* qp = Q + ((size_t)bh * SEQ + q0 + qg * 16 + qc) * DV + g * 8;
        qf[qg][0] = *(const f16x8*)(qp);
        qf[qg][1] = *(const f16x8*)(qp + 32);
    }

    float m_run[2] = {-1e30f, -1e30f}, l_run[2] = {0.f, 0.f};
    f32x4 oacc[2][4] = {};

#define STAGE(buf, kb)                                                          \
    {                                                                           \
        _Float16* kd = &Kb[buf][(w * 8) * 64];                                  \
        _Float16* vd = &Vb[buf][(w * 8) * 64];                                  \
        const int row = w * 8 + r8;                                             \
        gload16(Kg + (size_t)((kb) + row) * DV + cs, kd);                       \
        gload16(Kg + (size_t)((kb) + row + 32) * DV + cs, kd + 32 * 64);        \
        gload16(Vg + (size_t)row * SEQ + (kb) + cs, vd);                        \
        gload16(Vg + (size_t)(row + 32) * SEQ + (kb) + cs, vd + 32 * 64);       \
    }

    STAGE(0, 0);
    __syncthreads();

    for (int kt = 0; kt < 16; ++kt) {
        const int ct = kt & 1;
        if (kt < 15) STAGE(ct ^ 1, (kt + 1) * 64);
        const _Float16* Ktile = Kb[ct];
        const _Float16* Vtile = Vb[ct];

#pragma unroll
        for (int qg = 0; qg < 2; ++qg) {
            f32x4 sT[4];
            const f32x4 zf = {0.f, 0.f, 0.f, 0.f};
            __builtin_amdgcn_s_setprio(1);
#pragma unroll
            for (int kf = 0; kf < 4; ++kf) {
                const int row = kf * 16 + qc;
                f16x8 ka0 = *(const f16x8*)&Ktile[row * 64 + (((g)     ^ (qc & 7)) << 3)];
                f16x8 ka1 = *(const f16x8*)&Ktile[row * 64 + (((4 + g) ^ (qc & 7)) << 3)];
                f32x4 t = __builtin_amdgcn_mfma_f32_16x16x32_f16(ka0, qf[qg][0], zf, 0, 0, 0);
                sT[kf] = __builtin_amdgcn_mfma_f32_16x16x32_f16(ka1, qf[qg][1], t, 0, 0, 0);
            }
            __builtin_amdgcn_s_setprio(0);
            f32x4 mx = sT[0];
#pragma unroll
            for (int kf = 1; kf < 4; ++kf)
#pragma unroll
                for (int r = 0; r < 4; ++r) mx[r] = fmaxf(mx[r], sT[kf][r]);
            float pmax = fmaxf(fmaxf(mx[0], mx[1]), fmaxf(mx[2], mx[3]));
            pmax = fmaxf(pmax, __shfl_xor(pmax, 16));
            pmax = fmaxf(pmax, __shfl_xor(pmax, 32));
            if (!__all(pmax - m_run[qg] <= 8.0f)) {
                const float mn = fmaxf(m_run[qg], pmax);
                const float al = exp2f(m_run[qg] - mn);
                l_run[qg] *= al;
#pragma unroll
                for (int df = 0; df < 4; ++df) oacc[qg][df] *= al;
                m_run[qg] = mn;
            }
            float rsum = 0.f;
#pragma unroll
            for (int kf = 0; kf < 4; ++kf) {
                f16x4 ph;
#pragma unroll
                for (int r = 0; r < 4; ++r) {
                    const float p = exp2f(sT[kf][r] - m_run[qg]);
                    rsum += p;
                    ph[r] = (_Float16)p;
                }
                *(f16x4*)&P[w][qg][qc][kf * 16 + g * 4] = ph;
            }
            rsum += __shfl_xor(rsum, 16);
            rsum += __shfl_xor(rsum, 32);
            l_run[qg] += rsum;

            __builtin_amdgcn_s_setprio(1);
#pragma unroll
            for (int ks = 0; ks < 2; ++ks) {
                f16x8 pb = *(const f16x8*)&P[w][qg][qc][ks * 32 + g * 8];
#pragma unroll
                for (int df = 0; df < 4; ++df) {
                    const int row = df * 16 + qc;
                    f16x8 va = *(const f16x8*)&Vtile[row * 64 + (((ks * 4 + g) ^ (qc & 7)) << 3)];
                    oacc[qg][df] = __builtin_amdgcn_mfma_f32_16x16x32_f16(va, pb, oacc[qg][df], 0, 0, 0);
                }
            }
            __builtin_amdgcn_s_setprio(0);
        }
        __syncthreads();
    }
#undef STAGE

#pragma unroll
    for (int qg = 0; qg < 2; ++qg) {
        const float inv = 1.0f / l_run[qg];
        float* ob = out + ((size_t)b * SEQ + q0 + qg * 16 + qc) * D_MODEL + h * DV;
#pragma unroll
        for (int df = 0; df < 4; ++df) {
            float4 v4;
            v4.x = oacc[qg][df][0] * inv; v4.y = oacc[qg][df][1] * inv;
            v4.z = oacc[qg][df][2] * inv; v4.w = oacc[qg][df][3] * inv;
            *(float4*)(ob + df * 16 + g * 4) = v4;
        }
    }
}

extern "C" void kernel_launch(void* const* d_in, const int* in_sizes, int n_in,
                              void* d_out, int out_size, void* d_ws, size_t ws_size,
                              hipStream_t stream) {
    const float* seq = (const float*)d_in[0];
    const float* Wq  = (const float*)d_in[1];
    const float* bq  = (const float*)d_in[2];
    const float* Wk  = (const float*)d_in[3];
    const float* bk  = (const float*)d_in[4];
    const float* Wv  = (const float*)d_in[5];
    const float* bv  = (const float*)d_in[6];
    float* out = (float*)d_out;

    _Float16* seqh = (_Float16*)d_ws;
    _Float16* wqh  = seqh + (size_t)M_TOTAL * D_MODEL;
    _Float16* wkh  = wqh + (size_t)D_MODEL * D_MODEL;
    _Float16* wvh  = wkh + (size_t)D_MODEL * D_MODEL;
    _Float16* Qh   = wvh + (size_t)D_MODEL * D_MODEL;
    _Float16* Kh   = Qh + (size_t)M_TOTAL * D_MODEL;
    _Float16* Vth  = Kh + (size_t)M_TOTAL * D_MODEL;

    const int n_seq = M_TOTAL * D_MODEL;
    const int n_w   = D_MODEL * D_MODEL;
    cvt_f32_f16<<<n_seq / (256 * 8), 256, 0, stream>>>(seq, seqh, n_seq);
    cvt3_f32_f16<<<dim3(n_w / (256 * 8), 3), 256, 0, stream>>>(Wq, Wk, Wv, wqh, wkh, wvh, n_w);

    qkv_gemm<<<192, 512, 0, stream>>>(
        seqh, wqh, wkh, wvh, bq, bk, bv, Qh, Kh, Vth);

    attn<<<dim3(SEQ / QBLK, BATCH * NH), 256, 0, stream>>>(Qh, Kh, Vth, out);
}

// Round 5
// 91.808 us; speedup vs baseline: 1.2734x; 1.2734x over previous
//
#include <hip/hip_runtime.h>
#include <hip/hip_fp16.h>

typedef _Float16 f16x8 __attribute__((ext_vector_type(8)));
typedef _Float16 f16x4 __attribute__((ext_vector_type(4)));
typedef float f32x4 __attribute__((ext_vector_type(4)));

#define D_MODEL 1024
#define SEQ 1024
#define BATCH 4
#define NH 16
#define DV 64
#define M_TOTAL (BATCH * SEQ)   // 4096
#define QBLK 128

__device__ __forceinline__ void gload16(const _Float16* g, _Float16* lds) {
    __builtin_amdgcn_global_load_lds((const __attribute__((address_space(1))) void*)g,
                                     (__attribute__((address_space(3))) void*)lds,
                                     16, 0, 0);
}

// ---------------- fp32 -> fp16 convert (8 elems/thread) ----------------
__global__ void cvt_f32_f16(const float* __restrict__ s, _Float16* __restrict__ d, int n) {
    int i = (blockIdx.x * blockDim.x + threadIdx.x) * 8;
    if (i >= n) return;
    float4 a = *(const float4*)(s + i);
    float4 b = *(const float4*)(s + i + 4);
    f16x8 h;
    h[0] = (_Float16)a.x; h[1] = (_Float16)a.y; h[2] = (_Float16)a.z; h[3] = (_Float16)a.w;
    h[4] = (_Float16)b.x; h[5] = (_Float16)b.y; h[6] = (_Float16)b.z; h[7] = (_Float16)b.w;
    *(f16x8*)(d + i) = h;
}

__global__ void cvt3_f32_f16(const float* __restrict__ s0, const float* __restrict__ s1,
                             const float* __restrict__ s2, _Float16* __restrict__ d0,
                             _Float16* __restrict__ d1, _Float16* __restrict__ d2, int n) {
    const float* s = (blockIdx.y == 0) ? s0 : (blockIdx.y == 1 ? s1 : s2);
    _Float16*    d = (blockIdx.y == 0) ? d0 : (blockIdx.y == 1 ? d1 : d2);
    int i = (blockIdx.x * blockDim.x + threadIdx.x) * 8;
    if (i >= n) return;
    float4 a = *(const float4*)(s + i);
    float4 b = *(const float4*)(s + i + 4);
    f16x8 h;
    h[0] = (_Float16)a.x; h[1] = (_Float16)a.y; h[2] = (_Float16)a.z; h[3] = (_Float16)a.w;
    h[4] = (_Float16)b.x; h[5] = (_Float16)b.y; h[6] = (_Float16)b.z; h[7] = (_Float16)b.w;
    *(f16x8*)(d + i) = h;
}

// ---------------- fused QKV projection GEMM: 256x256 8-phase (T2+T3+T4+T5) ----------------
// Main loop unchanged from round 3 (verified correct). NEW: V-matrix epilogue goes
// through LDS (tile buffers are dead after the K-loop) so the transposed V^T output
// is written with coalesced 16B stores instead of 64-line 2B scatters.
__global__ __launch_bounds__(512, 2) void qkv_gemm(
    const _Float16* __restrict__ X,
    const _Float16* __restrict__ W0, const _Float16* __restrict__ W1, const _Float16* __restrict__ W2,
    const float* __restrict__ b0, const float* __restrict__ b1, const float* __restrict__ b2,
    _Float16* __restrict__ Qo, _Float16* __restrict__ Ko, _Float16* __restrict__ Vto)
{
    __shared__ _Float16 SM[4 * 256 * 64];   // [0,32K): A dbuf; [32K,64K): B dbuf; reused as 256x256 EP scratch
#define ABASE(buf) (SM + (buf) * 16384)
#define BBASE(buf) (SM + 32768 + (buf) * 16384)

    const int tid = threadIdx.x;
    const int l = tid & 63;
    const int w = tid >> 6;
    const int wr = w >> 2, wc = w & 3;

    // 192 blocks = 8 XCD x 24; ntg-contiguous per XCD (W panel L2-resident)
    const int bid = blockIdx.x;
    const int nid = (bid & 7) * 24 + (bid >> 3);
    const int mt = nid & 15, ntg = nid >> 4;      // ntg 0..11
    const int mat = ntg >> 2, nt = ntg & 3;       // mat: 0=Q 1=K 2=V
    const _Float16* Wm  = (mat == 0) ? W0 : (mat == 1 ? W1 : W2);
    const float*    bia = (mat == 0) ? b0 : (mat == 1 ? b1 : b2);
    const int m0 = mt * 256, n0 = nt * 256;

    // staging: thread t -> row (t>>3), dest chunk t&7, source chunk (t&7)^(row&7)
    const int str = tid >> 3;
    const int sc8 = ((tid & 7) ^ (str & 7)) * 8;
    const _Float16* xsrc = X  + (size_t)(m0 + str) * D_MODEL + sc8;
    const _Float16* wsrc = Wm + (size_t)(n0 + str) * D_MODEL + sc8;
    const int ldst = str * 64 + (tid & 7) * 8;

#define SA(buf, kt, h) do { \
    gload16(xsrc + (size_t)((h) * 128) * D_MODEL + (kt) * 64, ABASE(buf) + (h) * 8192 + ldst); \
    gload16(xsrc + (size_t)((h) * 128 + 64) * D_MODEL + (kt) * 64, ABASE(buf) + (h) * 8192 + 4096 + ldst); } while (0)
#define SB(buf, kt, h) do { \
    gload16(wsrc + (size_t)((h) * 128) * D_MODEL + (kt) * 64, BBASE(buf) + (h) * 8192 + ldst); \
    gload16(wsrc + (size_t)((h) * 128 + 64) * D_MODEL + (kt) * 64, BBASE(buf) + (h) * 8192 + 4096 + ldst); } while (0)

    const int fr = l & 15, g = l >> 4, fr7 = l & 7;
    const int wrow = wr * 128, bcol = wc * 64;

    f32x4 acc[8][4] = {};
    f16x8 b[4][2];

    // prologue: B(0), A(0), B(1)
    SB(0, 0, 0); SB(0, 0, 1);
    SA(0, 0, 0); SA(0, 0, 1);
    SB(1, 1, 0); SB(1, 1, 1);
    asm volatile("s_waitcnt vmcnt(4)" ::: "memory");
    __builtin_amdgcn_s_barrier();

#define PHASES(BUF, TSA_BUF, TSA, TSB_BUF, TSB)                                              \
    _Pragma("unroll")                                                                        \
    for (int p = 0; p < 4; ++p) {                                                            \
        if (p == 0) {                                                                        \
            _Pragma("unroll")                                                                \
            for (int nj = 0; nj < 4; ++nj) {                                                 \
                const int rb = (bcol + nj * 16 + fr) * 64;                                   \
                b[nj][0] = *(const f16x8*)&BBASE(BUF)[rb + ((g ^ fr7) << 3)];                \
                b[nj][1] = *(const f16x8*)&BBASE(BUF)[rb + (((4 + g) ^ fr7) << 3)];          \
            }                                                                                \
        }                                                                                    \
        f16x8 aq[2][2];                                                                      \
        _Pragma("unroll")                                                                    \
        for (int q = 0; q < 2; ++q) {                                                        \
            const int ra = (wrow + (2 * p + q) * 16 + fr) * 64;                              \
            aq[q][0] = *(const f16x8*)&ABASE(BUF)[ra + ((g ^ fr7) << 3)];                    \
            aq[q][1] = *(const f16x8*)&ABASE(BUF)[ra + (((4 + g) ^ fr7) << 3)];              \
        }                                                                                    \
        if (p == 0) SA(TSA_BUF, TSA, 0);                                                     \
        else if (p == 1) SA(TSA_BUF, TSA, 1);                                                \
        else if (p == 2) SB(TSB_BUF, TSB, 0);                                                \
        else SB(TSB_BUF, TSB, 1);                                                            \
        __builtin_amdgcn_s_barrier();                                                        \
        __builtin_amdgcn_s_setprio(1);                                                       \
        _Pragma("unroll")                                                                    \
        for (int ks = 0; ks < 2; ++ks)                                                       \
            _Pragma("unroll")                                                                \
            for (int q = 0; q < 2; ++q)                                                      \
                _Pragma("unroll")                                                            \
                for (int nj = 0; nj < 4; ++nj)                                               \
                    acc[2 * p + q][nj] = __builtin_amdgcn_mfma_f32_16x16x32_f16(             \
                        aq[q][ks], b[nj][ks], acc[2 * p + q][nj], 0, 0, 0);                  \
        __builtin_amdgcn_s_setprio(0);                                                       \
        if (p == 3) asm volatile("s_waitcnt vmcnt(4)" ::: "memory");                         \
        __builtin_amdgcn_s_barrier();                                                        \
    }

    for (int it = 0; it < 8; ++it) {
        const int tA = 2 * it + 1;
        const int tN = (2 * it + 2 < 16) ? 2 * it + 2 : 15;
        const int tM = (2 * it + 3 < 16) ? 2 * it + 3 : 15;
        PHASES(0, 1, tA, 0, tN)
        PHASES(1, 0, tN, 1, tM)
    }
#undef PHASES
#undef SA
#undef SB

    if (mat != 2) {
        // Q/K epilogue: bias + (Q) 0.125/ln2 scale; 32B-chunk stores (benign)
        const float scale = (mat == 0) ? 0.125f * 1.44269504088896340736f : 1.0f;
#pragma unroll
        for (int nj = 0; nj < 4; ++nj) {
            const int o = n0 + bcol + nj * 16 + fr;
            const float bb = bia[o];
            const int h = o >> 6, dd = o & 63;
#pragma unroll
            for (int mi = 0; mi < 8; ++mi) {
#pragma unroll
                for (int r = 0; r < 4; ++r) {
                    const int m = m0 + wrow + mi * 16 + g * 4 + r;
                    const int bi = m >> 10, s = m & 1023;
                    const float v = (acc[mi][nj][r] + bb) * scale;
                    const _Float16 hv = (_Float16)v;
                    const int bh = bi * NH + h;
                    if (mat == 0) Qo[((size_t)bh * SEQ + s) * DV + dd] = hv;
                    else          Ko[((size_t)bh * SEQ + s) * DV + dd] = hv;
                }
            }
        }
    } else {
        // V epilogue via LDS: transpose in LDS (chunk-rotated layout), coalesced 16B stores.
        // Drain in-flight global_load_lds (tail prefetches target this LDS!) before reuse.
        asm volatile("s_waitcnt vmcnt(0)" ::: "memory");
        __syncthreads();
        // phase 1: scatter acc -> EP[n][rot(m)]; addr_halves = n*256 + (((m>>3)+n)&31)*8 + (m&7)
#pragma unroll
        for (int nj = 0; nj < 4; ++nj) {
            const int n = bcol + nj * 16 + fr;
            const float bb = bia[n0 + n];
#pragma unroll
            for (int mi = 0; mi < 8; ++mi) {
#pragma unroll
                for (int r = 0; r < 4; ++r) {
                    const int m = wrow + mi * 16 + g * 4 + r;
                    SM[n * 256 + ((((m >> 3) + n) & 31) << 3) + (m & 7)] =
                        (_Float16)(acc[mi][nj][r] + bb);
                }
            }
        }
        __syncthreads();
        // phase 2: per task (dd, sc): read b128 = EP row dd, logical m-chunk sc; store 16B
        const int bi = m0 >> 10, s0 = m0 & 1023;
#pragma unroll
        for (int itp = 0; itp < 16; ++itp) {
            const int task = itp * 512 + tid;
            const int dd = task >> 5, sc = task & 31;
            f16x8 vv = *(const f16x8*)&SM[dd * 256 + (((sc + dd) & 31) << 3)];
            const int og = n0 + dd;
            const int h = og >> 6, d = og & 63;
            const int bh = bi * NH + h;
            *(f16x8*)(Vto + ((size_t)bh * DV + d) * SEQ + s0 + sc * 8) = vv;
        }
    }
#undef ABASE
#undef BBASE
}

// ---------------- flash attention (unchanged, known-good) ----------------
__global__ __launch_bounds__(256) void attn(
    const _Float16* __restrict__ Q, const _Float16* __restrict__ K,
    const _Float16* __restrict__ Vt, float* __restrict__ out)
{
    __shared__ _Float16 Kb[2][64 * 64];
    __shared__ _Float16 Vb[2][64 * 64];
    __shared__ _Float16 P[4][2][16][80];

    const int w = threadIdx.x >> 6, l = threadIdx.x & 63;
    const int qc = l & 15, g = l >> 4;

    const int fid = blockIdx.y * 8 + blockIdx.x;        // grid = (8, 64)
    const int nid = (fid & 7) * 64 + (fid >> 3);
    const int bh = nid >> 3, qt = nid & 7;
    const int b = bh >> 4, h = bh & 15;
    const int q0 = qt * QBLK + w * 32;

    const int r8 = l >> 3;
    const int cs = ((l & 7) ^ r8) * 8;
    const _Float16* Kg = K  + (size_t)bh * SEQ * DV;
    const _Float16* Vg = Vt + (size_t)bh * DV * SEQ;

    f16x8 qf[2][2];
#pragma unroll
    for (int qg = 0; qg < 2; ++qg) {
        const _Float16* qp = Q + ((size_t)bh * SEQ + q0 + qg * 16 + qc) * DV + g * 8;
        qf[qg][0] = *(const f16x8*)(qp);
        qf[qg][1] = *(const f16x8*)(qp + 32);
    }

    float m_run[2] = {-1e30f, -1e30f}, l_run[2] = {0.f, 0.f};
    f32x4 oacc[2][4] = {};

#define STAGE(buf, kb)                                                          \
    {                                                                           \
        _Float16* kd = &Kb[buf][(w * 8) * 64];                                  \
        _Float16* vd = &Vb[buf][(w * 8) * 64];                                  \
        const int row = w * 8 + r8;                                             \
        gload16(Kg + (size_t)((kb) + row) * DV + cs, kd);                       \
        gload16(Kg + (size_t)((kb) + row + 32) * DV + cs, kd + 32 * 64);        \
        gload16(Vg + (size_t)row * SEQ + (kb) + cs, vd);                        \
        gload16(Vg + (size_t)(row + 32) * SEQ + (kb) + cs, vd + 32 * 64);       \
    }

    STAGE(0, 0);
    __syncthreads();

    for (int kt = 0; kt < 16; ++kt) {
        const int ct = kt & 1;
        if (kt < 15) STAGE(ct ^ 1, (kt + 1) * 64);
        const _Float16* Ktile = Kb[ct];
        const _Float16* Vtile = Vb[ct];

#pragma unroll
        for (int qg = 0; qg < 2; ++qg) {
            f32x4 sT[4];
            const f32x4 zf = {0.f, 0.f, 0.f, 0.f};
            __builtin_amdgcn_s_setprio(1);
#pragma unroll
            for (int kf = 0; kf < 4; ++kf) {
                const int row = kf * 16 + qc;
                f16x8 ka0 = *(const f16x8*)&Ktile[row * 64 + (((g)     ^ (qc & 7)) << 3)];
                f16x8 ka1 = *(const f16x8*)&Ktile[row * 64 + (((4 + g) ^ (qc & 7)) << 3)];
                f32x4 t = __builtin_amdgcn_mfma_f32_16x16x32_f16(ka0, qf[qg][0], zf, 0, 0, 0);
                sT[kf] = __builtin_amdgcn_mfma_f32_16x16x32_f16(ka1, qf[qg][1], t, 0, 0, 0);
            }
            __builtin_amdgcn_s_setprio(0);
            f32x4 mx = sT[0];
#pragma unroll
            for (int kf = 1; kf < 4; ++kf)
#pragma unroll
                for (int r = 0; r < 4; ++r) mx[r] = fmaxf(mx[r], sT[kf][r]);
            float pmax = fmaxf(fmaxf(mx[0], mx[1]), fmaxf(mx[2], mx[3]));
            pmax = fmaxf(pmax, __shfl_xor(pmax, 16));
            pmax = fmaxf(pmax, __shfl_xor(pmax, 32));
            if (!__all(pmax - m_run[qg] <= 8.0f)) {
                const float mn = fmaxf(m_run[qg], pmax);
                const float al = exp2f(m_run[qg] - mn);
                l_run[qg] *= al;
#pragma unroll
                for (int df = 0; df < 4; ++df) oacc[qg][df] *= al;
                m_run[qg] = mn;
            }
            float rsum = 0.f;
#pragma unroll
            for (int kf = 0; kf < 4; ++kf) {
                f16x4 ph;
#pragma unroll
                for (int r = 0; r < 4; ++r) {
                    const float p = exp2f(sT[kf][r] - m_run[qg]);
                    rsum += p;
                    ph[r] = (_Float16)p;
                }
                *(f16x4*)&P[w][qg][qc][kf * 16 + g * 4] = ph;
            }
            rsum += __shfl_xor(rsum, 16);
            rsum += __shfl_xor(rsum, 32);
            l_run[qg] += rsum;

            __builtin_amdgcn_s_setprio(1);
#pragma unroll
            for (int ks = 0; ks < 2; ++ks) {
                f16x8 pb = *(const f16x8*)&P[w][qg][qc][ks * 32 + g * 8];
#pragma unroll
                for (int df = 0; df < 4; ++df) {
                    const int row = df * 16 + qc;
                    f16x8 va = *(const f16x8*)&Vtile[row * 64 + (((ks * 4 + g) ^ (qc & 7)) << 3)];
                    oacc[qg][df] = __builtin_amdgcn_mfma_f32_16x16x32_f16(va, pb, oacc[qg][df], 0, 0, 0);
                }
            }
            __builtin_amdgcn_s_setprio(0);
        }
        __syncthreads();
    }
#undef STAGE

#pragma unroll
    for (int qg = 0; qg < 2; ++qg) {
        const float inv = 1.0f / l_run[qg];
        float* ob = out + ((size_t)b * SEQ + q0 + qg * 16 + qc) * D_MODEL + h * DV;
#pragma unroll
        for (int df = 0; df < 4; ++df) {
            float4 v4;
            v4.x = oacc[qg][df][0] * inv; v4.y = oacc[qg][df][1] * inv;
            v4.z = oacc[qg][df][2] * inv; v4.w = oacc[qg][df][3] * inv;
            *(float4*)(ob + df * 16 + g * 4) = v4;
        }
    }
}

extern "C" void kernel_launch(void* const* d_in, const int* in_sizes, int n_in,
                              void* d_out, int out_size, void* d_ws, size_t ws_size,
                              hipStream_t stream) {
    const float* seq = (const float*)d_in[0];
    const float* Wq  = (const float*)d_in[1];
    const float* bq  = (const float*)d_in[2];
    const float* Wk  = (const float*)d_in[3];
    const float* bk  = (const float*)d_in[4];
    const float* Wv  = (const float*)d_in[5];
    const float* bv  = (const float*)d_in[6];
    float* out = (float*)d_out;

    _Float16* seqh = (_Float16*)d_ws;
    _Float16* wqh  = seqh + (size_t)M_TOTAL * D_MODEL;
    _Float16* wkh  = wqh + (size_t)D_MODEL * D_MODEL;
    _Float16* wvh  = wkh + (size_t)D_MODEL * D_MODEL;
    _Float16* Qh   = wvh + (size_t)D_MODEL * D_MODEL;
    _Float16* Kh   = Qh + (size_t)M_TOTAL * D_MODEL;
    _Float16* Vth  = Kh + (size_t)M_TOTAL * D_MODEL;

    const int n_seq = M_TOTAL * D_MODEL;
    const int n_w   = D_MODEL * D_MODEL;
    cvt_f32_f16<<<n_seq / (256 * 8), 256, 0, stream>>>(seq, seqh, n_seq);
    cvt3_f32_f16<<<dim3(n_w / (256 * 8), 3), 256, 0, stream>>>(Wq, Wk, Wv, wqh, wkh, wvh, n_w);

    qkv_gemm<<<192, 512, 0, stream>>>(
        seqh, wqh, wkh, wvh, bq, bk, bv, Qh, Kh, Vth);

    attn<<<dim3(SEQ / QBLK, BATCH * NH), 256, 0, stream>>>(Qh, Kh, Vth, out);
}

// Round 6
// 84.305 us; speedup vs baseline: 1.3867x; 1.0890x over previous
//
#include <hip/hip_runtime.h>
#include <hip/hip_fp16.h>

typedef _Float16 f16x8 __attribute__((ext_vector_type(8)));
typedef _Float16 f16x4 __attribute__((ext_vector_type(4)));
typedef float f32x4 __attribute__((ext_vector_type(4)));

#define D_MODEL 1024
#define SEQ 1024
#define BATCH 4
#define NH 16
#define DV 64
#define M_TOTAL (BATCH * SEQ)   // 4096
#define QBLK 128

__device__ __forceinline__ void gload16(const _Float16* g, _Float16* lds) {
    __builtin_amdgcn_global_load_lds((const __attribute__((address_space(1))) void*)g,
                                     (__attribute__((address_space(3))) void*)lds,
                                     16, 0, 0);
}

// ---------------- fp32 -> fp16 convert (8 elems/thread) ----------------
__global__ void cvt_f32_f16(const float* __restrict__ s, _Float16* __restrict__ d, int n) {
    int i = (blockIdx.x * blockDim.x + threadIdx.x) * 8;
    if (i >= n) return;
    float4 a = *(const float4*)(s + i);
    float4 b = *(const float4*)(s + i + 4);
    f16x8 h;
    h[0] = (_Float16)a.x; h[1] = (_Float16)a.y; h[2] = (_Float16)a.z; h[3] = (_Float16)a.w;
    h[4] = (_Float16)b.x; h[5] = (_Float16)b.y; h[6] = (_Float16)b.z; h[7] = (_Float16)b.w;
    *(f16x8*)(d + i) = h;
}

__global__ void cvt3_f32_f16(const float* __restrict__ s0, const float* __restrict__ s1,
                             const float* __restrict__ s2, _Float16* __restrict__ d0,
                             _Float16* __restrict__ d1, _Float16* __restrict__ d2, int n) {
    const float* s = (blockIdx.y == 0) ? s0 : (blockIdx.y == 1 ? s1 : s2);
    _Float16*    d = (blockIdx.y == 0) ? d0 : (blockIdx.y == 1 ? d1 : d2);
    int i = (blockIdx.x * blockDim.x + threadIdx.x) * 8;
    if (i >= n) return;
    float4 a = *(const float4*)(s + i);
    float4 b = *(const float4*)(s + i + 4);
    f16x8 h;
    h[0] = (_Float16)a.x; h[1] = (_Float16)a.y; h[2] = (_Float16)a.z; h[3] = (_Float16)a.w;
    h[4] = (_Float16)b.x; h[5] = (_Float16)b.y; h[6] = (_Float16)b.z; h[7] = (_Float16)b.w;
    *(f16x8*)(d + i) = h;
}

// ---------------- fused QKV projection GEMM: 256x256 8-phase (unchanged from round 4) ----------------
__global__ __launch_bounds__(512, 2) void qkv_gemm(
    const _Float16* __restrict__ X,
    const _Float16* __restrict__ W0, const _Float16* __restrict__ W1, const _Float16* __restrict__ W2,
    const float* __restrict__ b0, const float* __restrict__ b1, const float* __restrict__ b2,
    _Float16* __restrict__ Qo, _Float16* __restrict__ Ko, _Float16* __restrict__ Vto)
{
    __shared__ _Float16 SM[4 * 256 * 64];   // A dbuf | B dbuf; reused as 256x256 EP scratch
#define ABASE(buf) (SM + (buf) * 16384)
#define BBASE(buf) (SM + 32768 + (buf) * 16384)

    const int tid = threadIdx.x;
    const int l = tid & 63;
    const int w = tid >> 6;
    const int wr = w >> 2, wc = w & 3;

    const int bid = blockIdx.x;
    const int nid = (bid & 7) * 24 + (bid >> 3);
    const int mt = nid & 15, ntg = nid >> 4;
    const int mat = ntg >> 2, nt = ntg & 3;       // mat: 0=Q 1=K 2=V
    const _Float16* Wm  = (mat == 0) ? W0 : (mat == 1 ? W1 : W2);
    const float*    bia = (mat == 0) ? b0 : (mat == 1 ? b1 : b2);
    const int m0 = mt * 256, n0 = nt * 256;

    const int str = tid >> 3;
    const int sc8 = ((tid & 7) ^ (str & 7)) * 8;
    const _Float16* xsrc = X  + (size_t)(m0 + str) * D_MODEL + sc8;
    const _Float16* wsrc = Wm + (size_t)(n0 + str) * D_MODEL + sc8;
    const int ldst = str * 64 + (tid & 7) * 8;

#define SA(buf, kt, h) do { \
    gload16(xsrc + (size_t)((h) * 128) * D_MODEL + (kt) * 64, ABASE(buf) + (h) * 8192 + ldst); \
    gload16(xsrc + (size_t)((h) * 128 + 64) * D_MODEL + (kt) * 64, ABASE(buf) + (h) * 8192 + 4096 + ldst); } while (0)
#define SB(buf, kt, h) do { \
    gload16(wsrc + (size_t)((h) * 128) * D_MODEL + (kt) * 64, BBASE(buf) + (h) * 8192 + ldst); \
    gload16(wsrc + (size_t)((h) * 128 + 64) * D_MODEL + (kt) * 64, BBASE(buf) + (h) * 8192 + 4096 + ldst); } while (0)

    const int fr = l & 15, g = l >> 4, fr7 = l & 7;
    const int wrow = wr * 128, bcol = wc * 64;

    f32x4 acc[8][4] = {};
    f16x8 b[4][2];

    SB(0, 0, 0); SB(0, 0, 1);
    SA(0, 0, 0); SA(0, 0, 1);
    SB(1, 1, 0); SB(1, 1, 1);
    asm volatile("s_waitcnt vmcnt(4)" ::: "memory");
    __builtin_amdgcn_s_barrier();

#define PHASES(BUF, TSA_BUF, TSA, TSB_BUF, TSB)                                              \
    _Pragma("unroll")                                                                        \
    for (int p = 0; p < 4; ++p) {                                                            \
        if (p == 0) {                                                                        \
            _Pragma("unroll")                                                                \
            for (int nj = 0; nj < 4; ++nj) {                                                 \
                const int rb = (bcol + nj * 16 + fr) * 64;                                   \
                b[nj][0] = *(const f16x8*)&BBASE(BUF)[rb + ((g ^ fr7) << 3)];                \
                b[nj][1] = *(const f16x8*)&BBASE(BUF)[rb + (((4 + g) ^ fr7) << 3)];          \
            }                                                                                \
        }                                                                                    \
        f16x8 aq[2][2];                                                                      \
        _Pragma("unroll")                                                                    \
        for (int q = 0; q < 2; ++q) {                                                        \
            const int ra = (wrow + (2 * p + q) * 16 + fr) * 64;                              \
            aq[q][0] = *(const f16x8*)&ABASE(BUF)[ra + ((g ^ fr7) << 3)];                    \
            aq[q][1] = *(const f16x8*)&ABASE(BUF)[ra + (((4 + g) ^ fr7) << 3)];              \
        }                                                                                    \
        if (p == 0) SA(TSA_BUF, TSA, 0);                                                     \
        else if (p == 1) SA(TSA_BUF, TSA, 1);                                                \
        else if (p == 2) SB(TSB_BUF, TSB, 0);                                                \
        else SB(TSB_BUF, TSB, 1);                                                            \
        __builtin_amdgcn_s_barrier();                                                        \
        __builtin_amdgcn_s_setprio(1);                                                       \
        _Pragma("unroll")                                                                    \
        for (int ks = 0; ks < 2; ++ks)                                                       \
            _Pragma("unroll")                                                                \
            for (int q = 0; q < 2; ++q)                                                      \
                _Pragma("unroll")                                                            \
                for (int nj = 0; nj < 4; ++nj)                                               \
                    acc[2 * p + q][nj] = __builtin_amdgcn_mfma_f32_16x16x32_f16(             \
                        aq[q][ks], b[nj][ks], acc[2 * p + q][nj], 0, 0, 0);                  \
        __builtin_amdgcn_s_setprio(0);                                                       \
        if (p == 3) asm volatile("s_waitcnt vmcnt(4)" ::: "memory");                         \
        __builtin_amdgcn_s_barrier();                                                        \
    }

    for (int it = 0; it < 8; ++it) {
        const int tA = 2 * it + 1;
        const int tN = (2 * it + 2 < 16) ? 2 * it + 2 : 15;
        const int tM = (2 * it + 3 < 16) ? 2 * it + 3 : 15;
        PHASES(0, 1, tA, 0, tN)
        PHASES(1, 0, tN, 1, tM)
    }
#undef PHASES
#undef SA
#undef SB

    if (mat != 2) {
        const float scale = (mat == 0) ? 0.125f * 1.44269504088896340736f : 1.0f;
#pragma unroll
        for (int nj = 0; nj < 4; ++nj) {
            const int o = n0 + bcol + nj * 16 + fr;
            const float bb = bia[o];
            const int h = o >> 6, dd = o & 63;
#pragma unroll
            for (int mi = 0; mi < 8; ++mi) {
#pragma unroll
                for (int r = 0; r < 4; ++r) {
                    const int m = m0 + wrow + mi * 16 + g * 4 + r;
                    const int bi = m >> 10, s = m & 1023;
                    const float v = (acc[mi][nj][r] + bb) * scale;
                    const _Float16 hv = (_Float16)v;
                    const int bh = bi * NH + h;
                    if (mat == 0) Qo[((size_t)bh * SEQ + s) * DV + dd] = hv;
                    else          Ko[((size_t)bh * SEQ + s) * DV + dd] = hv;
                }
            }
        }
    } else {
        // V epilogue via LDS: transpose + coalesced 16B stores
        asm volatile("s_waitcnt vmcnt(0)" ::: "memory");
        __syncthreads();
#pragma unroll
        for (int nj = 0; nj < 4; ++nj) {
            const int n = bcol + nj * 16 + fr;
            const float bb = bia[n0 + n];
#pragma unroll
            for (int mi = 0; mi < 8; ++mi) {
#pragma unroll
                for (int r = 0; r < 4; ++r) {
                    const int m = wrow + mi * 16 + g * 4 + r;
                    SM[n * 256 + ((((m >> 3) + n) & 31) << 3) + (m & 7)] =
                        (_Float16)(acc[mi][nj][r] + bb);
                }
            }
        }
        __syncthreads();
        const int bi = m0 >> 10, s0 = m0 & 1023;
#pragma unroll
        for (int itp = 0; itp < 16; ++itp) {
            const int task = itp * 512 + tid;
            const int dd = task >> 5, sc = task & 31;
            f16x8 vv = *(const f16x8*)&SM[dd * 256 + (((sc + dd) & 31) << 3)];
            const int og = n0 + dd;
            const int h = og >> 6, d = og & 63;
            const int bh = bi * NH + h;
            *(f16x8*)(Vto + ((size_t)bh * DV + d) * SEQ + s0 + sc * 8) = vv;
        }
    }
#undef ABASE
#undef BBASE
}

// ---------------- flash attention: 8 waves/block, 16 q-rows/wave ----------------
// grid 512 blocks (XCD-swizzled) x 512 threads. QBLK=128. K,V 64x64 tiles double-
// buffered in LDS (1 K + 1 V global_load_lds per thread per tile), XOR chunk-swizzle
// via pre-swizzled global source. 2 blocks/CU -> 16 waves/CU (2x round-5 occupancy).
__global__ __launch_bounds__(512, 4) void attn(
    const _Float16* __restrict__ Q, const _Float16* __restrict__ K,
    const _Float16* __restrict__ Vt, float* __restrict__ out)
{
    __shared__ _Float16 Kb[2][64 * 64];
    __shared__ _Float16 Vb[2][64 * 64];
    __shared__ _Float16 P[8][16][80];

    const int tid = threadIdx.x;
    const int w = tid >> 6, l = tid & 63;
    const int qc = l & 15, g = l >> 4;

    // XCD swizzle: all 8 q-tiles of a head land on one XCD (512 % 8 == 0, bijective)
    const int fid = blockIdx.y * 8 + blockIdx.x;        // grid = (8, 64)
    const int nid = (fid & 7) * 64 + (fid >> 3);
    const int bh = nid >> 3, qt = nid & 7;
    const int b = bh >> 4, h = bh & 15;
    const int q0 = qt * QBLK + w * 16;

    // staging: thread covers row tid>>3, dest chunk tid&7, src chunk swizzled
    const int str = tid >> 3;
    const int scs = ((tid & 7) ^ (str & 7)) * 8;
    const int ldst = str * 64 + (tid & 7) * 8;
    const _Float16* Kg = K  + (size_t)bh * SEQ * DV;
    const _Float16* Vg = Vt + (size_t)bh * DV * SEQ;

    const _Float16* qp = Q + ((size_t)bh * SEQ + q0 + qc) * DV + g * 8;
    f16x8 qf0 = *(const f16x8*)(qp);
    f16x8 qf1 = *(const f16x8*)(qp + 32);

    float m_run = -1e30f, l_run = 0.f;
    f32x4 oacc[4] = {};

#define STAGE(buf, kb) do {                                                  \
        gload16(Kg + (size_t)((kb) + str) * DV + scs, &Kb[buf][0] + ldst);   \
        gload16(Vg + (size_t)str * SEQ + (kb) + scs, &Vb[buf][0] + ldst);    \
    } while (0)

    STAGE(0, 0);
    __syncthreads();   // drains vmcnt(0): tile 0 ready

    for (int kt = 0; kt < 16; ++kt) {
        const int ct = kt & 1;
        if (kt < 15) STAGE(ct ^ 1, (kt + 1) * 64);   // prefetch next tile under compute
        const _Float16* Ktile = Kb[ct];
        const _Float16* Vtile = Vb[ct];

        // ---- QK^T (swapped: scoresT), K from swizzled LDS ----
        f32x4 sT[4];
        const f32x4 zf = {0.f, 0.f, 0.f, 0.f};
        __builtin_amdgcn_s_setprio(1);
#pragma unroll
        for (int kf = 0; kf < 4; ++kf) {
            const int row = kf * 16 + qc;
            f16x8 ka0 = *(const f16x8*)&Ktile[row * 64 + (((g)     ^ (qc & 7)) << 3)];
            f16x8 ka1 = *(const f16x8*)&Ktile[row * 64 + (((4 + g) ^ (qc & 7)) << 3)];
            f32x4 t = __builtin_amdgcn_mfma_f32_16x16x32_f16(ka0, qf0, zf, 0, 0, 0);
            sT[kf] = __builtin_amdgcn_mfma_f32_16x16x32_f16(ka1, qf1, t, 0, 0, 0);
        }
        __builtin_amdgcn_s_setprio(0);

        // ---- online softmax (log2 domain; scores pre-scaled by 1/ln2) ----
        f32x4 mx = sT[0];
#pragma unroll
        for (int kf = 1; kf < 4; ++kf)
#pragma unroll
            for (int r = 0; r < 4; ++r) mx[r] = fmaxf(mx[r], sT[kf][r]);
        float pmax = fmaxf(fmaxf(mx[0], mx[1]), fmaxf(mx[2], mx[3]));
        pmax = fmaxf(pmax, __shfl_xor(pmax, 16));
        pmax = fmaxf(pmax, __shfl_xor(pmax, 32));
        if (!__all(pmax - m_run <= 8.0f)) {     // T13 defer-rescale (P <= 2^8)
            const float mn = fmaxf(m_run, pmax);
            const float al = exp2f(m_run - mn);
            l_run *= al;
#pragma unroll
            for (int df = 0; df < 4; ++df) oacc[df] *= al;
            m_run = mn;
        }
        float rsum = 0.f;
#pragma unroll
        for (int kf = 0; kf < 4; ++kf) {
            f16x4 ph;
#pragma unroll
            for (int r = 0; r < 4; ++r) {
                const float p = exp2f(sT[kf][r] - m_run);
                rsum += p;
                ph[r] = (_Float16)p;
            }
            *(f16x4*)&P[w][qc][kf * 16 + g * 4] = ph;
        }
        rsum += __shfl_xor(rsum, 16);
        rsum += __shfl_xor(rsum, 32);
        l_run += rsum;

        // ---- PV (transposed), V from swizzled LDS ----
        __builtin_amdgcn_s_setprio(1);
#pragma unroll
        for (int ks = 0; ks < 2; ++ks) {
            f16x8 pb = *(const f16x8*)&P[w][qc][ks * 32 + g * 8];
#pragma unroll
            for (int df = 0; df < 4; ++df) {
                const int row = df * 16 + qc;
                f16x8 va = *(const f16x8*)&Vtile[row * 64 + (((ks * 4 + g) ^ (qc & 7)) << 3)];
                oacc[df] = __builtin_amdgcn_mfma_f32_16x16x32_f16(va, pb, oacc[df], 0, 0, 0);
            }
        }
        __builtin_amdgcn_s_setprio(0);

        __syncthreads();   // drains vmcnt(0): next tile staged + all waves done with cur
    }
#undef STAGE

    const float inv = 1.0f / l_run;
    float* ob = out + ((size_t)b * SEQ + q0 + qc) * D_MODEL + h * DV;
#pragma unroll
    for (int df = 0; df < 4; ++df) {
        float4 v4;
        v4.x = oacc[df][0] * inv; v4.y = oacc[df][1] * inv;
        v4.z = oacc[df][2] * inv; v4.w = oacc[df][3] * inv;
        *(float4*)(ob + df * 16 + g * 4) = v4;
    }
}

extern "C" void kernel_launch(void* const* d_in, const int* in_sizes, int n_in,
                              void* d_out, int out_size, void* d_ws, size_t ws_size,
                              hipStream_t stream) {
    const float* seq = (const float*)d_in[0];
    const float* Wq  = (const float*)d_in[1];
    const float* bq  = (const float*)d_in[2];
    const float* Wk  = (const float*)d_in[3];
    const float* bk  = (const float*)d_in[4];
    const float* Wv  = (const float*)d_in[5];
    const float* bv  = (const float*)d_in[6];
    float* out = (float*)d_out;

    _Float16* seqh = (_Float16*)d_ws;
    _Float16* wqh  = seqh + (size_t)M_TOTAL * D_MODEL;
    _Float16* wkh  = wqh + (size_t)D_MODEL * D_MODEL;
    _Float16* wvh  = wkh + (size_t)D_MODEL * D_MODEL;
    _Float16* Qh   = wvh + (size_t)D_MODEL * D_MODEL;
    _Float16* Kh   = Qh + (size_t)M_TOTAL * D_MODEL;
    _Float16* Vth  = Kh + (size_t)M_TOTAL * D_MODEL;

    const int n_seq = M_TOTAL * D_MODEL;
    const int n_w   = D_MODEL * D_MODEL;
    cvt_f32_f16<<<n_seq / (256 * 8), 256, 0, stream>>>(seq, seqh, n_seq);
    cvt3_f32_f16<<<dim3(n_w / (256 * 8), 3), 256, 0, stream>>>(Wq, Wk, Wv, wqh, wkh, wvh, n_w);

    qkv_gemm<<<192, 512, 0, stream>>>(
        seqh, wqh, wkh, wvh, bq, bk, bv, Qh, Kh, Vth);

    attn<<<dim3(SEQ / QBLK, BATCH * NH), 512, 0, stream>>>(Qh, Kh, Vth, out);
}